// Round 1
// baseline (249.432 us; speedup 1.0000x reference)
//
#include <hip/hip_runtime.h>

// Problem: SwitchTransformersLoadBalancer
//   x: (B=64, C=8, H=256, W=256) f32, accumulator: (256, 8) f32
//   out = one_hot(argmax_c softmax(x)/mean(acc)_c renormalized) == 
//         one_hot(argmax_c (x_c - log(mean(acc[:,c]))))
// Memory-bound streaming kernel: 134 MB in + 134 MB out.

#define PLANE 65536            // H*W elements per (b,c) plane
#define PLANE4 16384           // plane stride in float4 units

// Tiny kernel: lognorm[c] = log(mean(accumulator[:, c])), c = 0..7.
// accumulator is row-major (256, 8).
__global__ void norm_kernel(const float* __restrict__ acc,
                            double* __restrict__ lognorm) {
    int c = threadIdx.x;
    if (c < 8) {
        double s = 0.0;
        #pragma unroll 8
        for (int i = 0; i < 256; ++i) s += (double)acc[i * 8 + c];
        lognorm[c] = log(s * (1.0 / 256.0));
    }
}

// Main kernel: one thread handles 4 consecutive pixels (one float4 per expert
// plane). Argmax over 8 experts in f64, write 8-channel one-hot as float4s.
__global__ __launch_bounds__(256) void route_kernel(const float* __restrict__ x,
                                                    const double* __restrict__ lognorm,
                                                    float* __restrict__ out) {
    int tid = blockIdx.x * 256 + threadIdx.x;
    int i4  = tid << 2;            // first pixel index within (B*H*W)
    int b   = i4 >> 16;            // batch (plane = 65536 pixels)
    int p   = i4 & 65535;          // pixel offset inside plane (multiple of 4)

    double ln[8];
    #pragma unroll
    for (int c = 0; c < 8; ++c) ln[c] = lognorm[c];   // L1/L2 broadcast hits

    const float4* xb = (const float4*)(x + ((size_t)(b * 8) << 16)) + (p >> 2);

    float4 v = xb[0];
    double best0 = (double)v.x - ln[0];
    double best1 = (double)v.y - ln[0];
    double best2 = (double)v.z - ln[0];
    double best3 = (double)v.w - ln[0];
    int idx0 = 0, idx1 = 0, idx2 = 0, idx3 = 0;

    #pragma unroll
    for (int c = 1; c < 8; ++c) {
        float4 u = xb[c * PLANE4];
        double d;
        d = (double)u.x - ln[c]; if (d > best0) { best0 = d; idx0 = c; }
        d = (double)u.y - ln[c]; if (d > best1) { best1 = d; idx1 = c; }
        d = (double)u.z - ln[c]; if (d > best2) { best2 = d; idx2 = c; }
        d = (double)u.w - ln[c]; if (d > best3) { best3 = d; idx3 = c; }
    }

    float4* ob = (float4*)(out + ((size_t)(b * 8) << 16)) + (p >> 2);
    #pragma unroll
    for (int c = 0; c < 8; ++c) {
        float4 o;
        o.x = (idx0 == c) ? 1.0f : 0.0f;
        o.y = (idx1 == c) ? 1.0f : 0.0f;
        o.z = (idx2 == c) ? 1.0f : 0.0f;
        o.w = (idx3 == c) ? 1.0f : 0.0f;
        ob[c * PLANE4] = o;
    }
}

extern "C" void kernel_launch(void* const* d_in, const int* in_sizes, int n_in,
                              void* d_out, int out_size, void* d_ws, size_t ws_size,
                              hipStream_t stream) {
    const float* x   = (const float*)d_in[0];   // (64, 8, 256, 256)
    const float* acc = (const float*)d_in[1];   // (256, 8)
    float*       out = (float*)d_out;           // (64, 8, 256, 256)
    double* lognorm  = (double*)d_ws;           // 8 doubles of scratch

    norm_kernel<<<1, 64, 0, stream>>>(acc, lognorm);

    // B*H*W = 4,194,304 pixels; 4 pixels/thread -> 1,048,576 threads.
    route_kernel<<<4096, 256, 0, stream>>>(x, lognorm, out);
}

// Round 2
// 234.438 us; speedup vs baseline: 1.0640x; 1.0640x over previous
//
#include <hip/hip_runtime.h>

// SwitchTransformersLoadBalancer:
//   x: (B=64, C=8, H=256, W=256) f32, accumulator: (256, 8) f32
//   out = one_hot(argmax_c (x_c - log(mean(acc[:,c]))))   [proved in R0, absmax 0]
// Streaming: 128 MiB read + 128 MiB write. Floor ~43 us at 6.3 TB/s.

#define PLANE4 16384   // plane stride in float4 units (65536 floats)

typedef float fvec4 __attribute__((ext_vector_type(4)));

// lognorm[c] = log(mean(accumulator[:, c])). Parallel partial sums (8 loads
// per thread, coalesced-ish over the 8 KB buffer) + LDS reduce. Was a serial
// 256-deep load chain on 8 lanes (~10 us latency-bound); now ~2 us.
__global__ __launch_bounds__(256) void norm_kernel(const float* __restrict__ acc,
                                                   double* __restrict__ lognorm) {
    __shared__ double part[256];
    int t = threadIdx.x;
    int c = t & 7;        // channel
    int g = t >> 3;       // row group, 0..31
    double s = 0.0;
    #pragma unroll
    for (int k = 0; k < 8; ++k) s += (double)acc[(g * 8 + k) * 8 + c];
    part[t] = s;
    __syncthreads();
    if (t < 8) {
        double tot = 0.0;
        #pragma unroll
        for (int g2 = 0; g2 < 32; ++g2) tot += part[g2 * 8 + t];
        lognorm[t] = log(tot * (1.0 / 256.0));
    }
}

// One thread = 4 consecutive pixels. 8 coalesced float4 loads (one per expert
// plane), f64 argmax (exact vs f32 reference; strict > keeps first-index
// tie-break), 8 NONTEMPORAL float4 stores — out is write-once, keep L2/LLC
// for x (which the harness restore-copy just made LLC-resident).
__global__ __launch_bounds__(256) void route_kernel(const float* __restrict__ x,
                                                    const double* __restrict__ lognorm,
                                                    float* __restrict__ out) {
    int tid = blockIdx.x * 256 + threadIdx.x;
    int i4  = tid << 2;            // first pixel index within (B*H*W)
    int b   = i4 >> 16;            // batch (plane = 65536 pixels)
    int p4  = (i4 & 65535) >> 2;   // float4 offset inside plane

    double ln[8];
    #pragma unroll
    for (int c = 0; c < 8; ++c) ln[c] = lognorm[c];   // uniform -> s_load

    const fvec4* xb = (const fvec4*)(x + ((size_t)(b * 8) << 16)) + p4;

    fvec4 v = xb[0];
    double best0 = (double)v.x - ln[0];
    double best1 = (double)v.y - ln[0];
    double best2 = (double)v.z - ln[0];
    double best3 = (double)v.w - ln[0];
    int idx0 = 0, idx1 = 0, idx2 = 0, idx3 = 0;

    #pragma unroll
    for (int c = 1; c < 8; ++c) {
        fvec4 u = xb[c * PLANE4];
        double d;
        d = (double)u.x - ln[c]; if (d > best0) { best0 = d; idx0 = c; }
        d = (double)u.y - ln[c]; if (d > best1) { best1 = d; idx1 = c; }
        d = (double)u.z - ln[c]; if (d > best2) { best2 = d; idx2 = c; }
        d = (double)u.w - ln[c]; if (d > best3) { best3 = d; idx3 = c; }
    }

    fvec4* ob = (fvec4*)(out + ((size_t)(b * 8) << 16)) + p4;
    #pragma unroll
    for (int c = 0; c < 8; ++c) {
        fvec4 o;
        o.x = (idx0 == c) ? 1.0f : 0.0f;
        o.y = (idx1 == c) ? 1.0f : 0.0f;
        o.z = (idx2 == c) ? 1.0f : 0.0f;
        o.w = (idx3 == c) ? 1.0f : 0.0f;
        __builtin_nontemporal_store(o, ob + c * PLANE4);
    }
}

extern "C" void kernel_launch(void* const* d_in, const int* in_sizes, int n_in,
                              void* d_out, int out_size, void* d_ws, size_t ws_size,
                              hipStream_t stream) {
    const float* x   = (const float*)d_in[0];   // (64, 8, 256, 256)
    const float* acc = (const float*)d_in[1];   // (256, 8)
    float*       out = (float*)d_out;           // (64, 8, 256, 256)
    double* lognorm  = (double*)d_ws;           // 8 doubles of scratch

    norm_kernel<<<1, 256, 0, stream>>>(acc, lognorm);

    // B*H*W = 4,194,304 pixels; 4 pixels/thread -> 1,048,576 threads.
    route_kernel<<<4096, 256, 0, stream>>>(x, lognorm, out);
}

// Round 3
// 232.399 us; speedup vs baseline: 1.0733x; 1.0088x over previous
//
#include <hip/hip_runtime.h>

// SwitchTransformersLoadBalancer:
//   x: (B=64, C=8, H=256, W=256) f32, accumulator: (256, 8) f32
//   out = one_hot(argmax_c (x_c - log(mean(acc[:,c]))))   [proved R0/R1, absmax 0]
// Streaming: 128 MiB read + 128 MiB write -> ~41 us floor at 6.3 TB/s.
// R2: fused single kernel — each block redundantly computes the 8 log-mean
// values from the 8 KB accumulator (L2/LLC broadcast), removing the separate
// norm dispatch + its graph dependency bubble. x loads issued BEFORE the
// reduce so they hide it.

#define PLANE4 16384   // plane stride in float4 units (65536 floats)

typedef float fvec4 __attribute__((ext_vector_type(4)));

__global__ __launch_bounds__(256) void fused_route_kernel(
        const float* __restrict__ x,
        const float* __restrict__ acc,
        float* __restrict__ out) {
    int t   = threadIdx.x;
    int tid = blockIdx.x * 256 + t;
    int i4  = tid << 2;            // first pixel index within (B*H*W)
    int b   = i4 >> 16;            // batch (plane = 65536 pixels)
    int p4  = (i4 & 65535) >> 2;   // float4 offset inside plane

    // ---- issue the 8 streaming x loads first (independent of the reduce) ----
    const fvec4* xb = (const fvec4*)(x + ((size_t)(b * 8) << 16)) + p4;
    fvec4 u[8];
    #pragma unroll
    for (int c = 0; c < 8; ++c) u[c] = xb[c * PLANE4];

    // ---- per-block lognorm: 8 KB accumulator -> LDS reduce -> log(mean) ----
    __shared__ double part[256];
    __shared__ double lns[8];
    {
        int c = t & 7;        // channel
        int g = t >> 3;       // row group, 0..31
        double s = 0.0;
        #pragma unroll
        for (int k = 0; k < 8; ++k) s += (double)acc[(g * 8 + k) * 8 + c];
        part[t] = s;
    }
    __syncthreads();
    if (t < 8) {
        double tot = 0.0;
        #pragma unroll
        for (int g2 = 0; g2 < 32; ++g2) tot += part[g2 * 8 + t];
        lns[t] = log(tot * (1.0 / 256.0));
    }
    __syncthreads();

    double ln[8];
    #pragma unroll
    for (int c = 0; c < 8; ++c) ln[c] = lns[c];   // same-address -> LDS broadcast

    // ---- f64 argmax (exact vs f32 reference; strict > = first-index ties) ----
    double best0 = (double)u[0].x - ln[0];
    double best1 = (double)u[0].y - ln[0];
    double best2 = (double)u[0].z - ln[0];
    double best3 = (double)u[0].w - ln[0];
    int idx0 = 0, idx1 = 0, idx2 = 0, idx3 = 0;

    #pragma unroll
    for (int c = 1; c < 8; ++c) {
        double d;
        d = (double)u[c].x - ln[c]; if (d > best0) { best0 = d; idx0 = c; }
        d = (double)u[c].y - ln[c]; if (d > best1) { best1 = d; idx1 = c; }
        d = (double)u[c].z - ln[c]; if (d > best2) { best2 = d; idx2 = c; }
        d = (double)u[c].w - ln[c]; if (d > best3) { best3 = d; idx3 = c; }
    }

    // ---- nontemporal one-hot stores (write-once, bypass LLC alloc) ----
    fvec4* ob = (fvec4*)(out + ((size_t)(b * 8) << 16)) + p4;
    #pragma unroll
    for (int c = 0; c < 8; ++c) {
        fvec4 o;
        o.x = (idx0 == c) ? 1.0f : 0.0f;
        o.y = (idx1 == c) ? 1.0f : 0.0f;
        o.z = (idx2 == c) ? 1.0f : 0.0f;
        o.w = (idx3 == c) ? 1.0f : 0.0f;
        __builtin_nontemporal_store(o, ob + c * PLANE4);
    }
}

extern "C" void kernel_launch(void* const* d_in, const int* in_sizes, int n_in,
                              void* d_out, int out_size, void* d_ws, size_t ws_size,
                              hipStream_t stream) {
    const float* x   = (const float*)d_in[0];   // (64, 8, 256, 256)
    const float* acc = (const float*)d_in[1];   // (256, 8)
    float*       out = (float*)d_out;           // (64, 8, 256, 256)
    (void)d_ws; (void)ws_size;

    // B*H*W = 4,194,304 pixels; 4 pixels/thread -> 1,048,576 threads.
    fused_route_kernel<<<4096, 256, 0, stream>>>(x, acc, out);
}